// Round 7
// baseline (409.052 us; speedup 1.0000x reference)
//
#include <hip/hip_runtime.h>
#include <hip/hip_bf16.h>

// Fused LayerNorm + QKV projection for B=4, S=2048, H=2048 (fp32 in/out).
//
// Round 7: 256x256/BK=64/8-wave structure with ONE-PHASE REGISTER LOOKAHEAD:
// phase p issues the ds_reads for phase p+1's fragments, then runs phase p's
// MFMAs from registers -> LDS pipe and matrix pipe overlap instead of
// alternating (round 3/6 were serialized: MfmaUtil 35% = MFMA/(MFMA+LDS)).
// vmcnt guards moved BEFORE the cross-buffer lookahead reads (ledger
// re-derived; last iteration uses vmcnt(0) since skipped stages break the
// vmcnt(6) proof). Double register sets x/y (A) and cbA/cbB (B), all
// constant-indexed.

#define HD   2048            // hidden dim (K)
#define MTOT 8192            // B*S rows
#define NTOT 6144            // 3*H packed output cols
#define NIT  16              // iterations (2 K-tiles of BK=64 each)

typedef __attribute__((ext_vector_type(8))) _Float16 f16x8;   // 4 VGPR
typedef __attribute__((ext_vector_type(4))) _Float16 f16x4;
typedef __attribute__((ext_vector_type(4))) float f32x4;

// ---------------------------------------------------------------------------
// Kernel 1: LayerNorm -> fp16.  One block per row, 256 threads, 8 elems each.
// ---------------------------------------------------------------------------
__global__ __launch_bounds__(256) void ln_f16_kernel(
    const float* __restrict__ x, const float* __restrict__ gamma,
    const float* __restrict__ beta, _Float16* __restrict__ hi) {
  const int row = blockIdx.x;
  const float* xr = x + (size_t)row * HD;
  const int t = threadIdx.x;

  float4 v0 = reinterpret_cast<const float4*>(xr)[t * 2];
  float4 v1 = reinterpret_cast<const float4*>(xr)[t * 2 + 1];
  float xs[8] = {v0.x, v0.y, v0.z, v0.w, v1.x, v1.y, v1.z, v1.w};

  float s = 0.f, q = 0.f;
#pragma unroll
  for (int j = 0; j < 8; ++j) { s += xs[j]; q += xs[j] * xs[j]; }
#pragma unroll
  for (int off = 32; off; off >>= 1) {
    s += __shfl_down(s, off);
    q += __shfl_down(q, off);
  }
  __shared__ float red[8];
  const int wid = t >> 6, lane = t & 63;
  if (lane == 0) { red[wid] = s; red[4 + wid] = q; }
  __syncthreads();
  s = red[0] + red[1] + red[2] + red[3];
  q = red[4] + red[5] + red[6] + red[7];
  const float mu  = s * (1.f / HD);
  const float var = q * (1.f / HD) - mu * mu;
  const float rs  = rsqrtf(var + 1e-5f);

  float4 g0 = reinterpret_cast<const float4*>(gamma)[t * 2];
  float4 g1 = reinterpret_cast<const float4*>(gamma)[t * 2 + 1];
  float4 b0 = reinterpret_cast<const float4*>(beta)[t * 2];
  float4 b1 = reinterpret_cast<const float4*>(beta)[t * 2 + 1];
  float gs[8] = {g0.x, g0.y, g0.z, g0.w, g1.x, g1.y, g1.z, g1.w};
  float bs[8] = {b0.x, b0.y, b0.z, b0.w, b1.x, b1.y, b1.z, b1.w};

  f16x8 hv;
#pragma unroll
  for (int j = 0; j < 8; ++j) {
    float y = (xs[j] - mu) * rs * gs[j] + bs[j];
    hv[j] = (_Float16)y;
  }
  *reinterpret_cast<f16x8*>(&hi[(size_t)row * HD + t * 8]) = hv;
}

// ---------------------------------------------------------------------------
// Kernel 2: weights -> fp16 (q, k, v stacked).
// ---------------------------------------------------------------------------
__global__ __launch_bounds__(256) void w_f16_kernel(
    const float* __restrict__ qw, const float* __restrict__ kw,
    const float* __restrict__ vw, _Float16* __restrict__ hi) {
  const int m = blockIdx.y;
  const float* src = (m == 0) ? qw : (m == 1) ? kw : vw;
  const size_t base = (size_t)m * HD * HD;
  const int total4 = HD * HD / 4;
  for (int i = blockIdx.x * blockDim.x + threadIdx.x; i < total4;
       i += gridDim.x * blockDim.x) {
    float4 v = reinterpret_cast<const float4*>(src)[i];
    f16x4 hv;
    hv[0] = (_Float16)v.x; hv[1] = (_Float16)v.y;
    hv[2] = (_Float16)v.z; hv[3] = (_Float16)v.w;
    *reinterpret_cast<f16x4*>(&hi[base + (size_t)i * 4]) = hv;
  }
}

// ---------------------------------------------------------------------------
// Kernel 3: 256x256 8-phase fp16 GEMM with one-phase register lookahead.
// out[m][n] = sum_k A[m][k] * W_p[n][k] + bias_p[n]
//
// LDS (128 KiB, f16 units): A bufs at {0, 16384}, B bufs at {32768, 49152};
// buffer = 8 kb-planes x 256 rows x 8 f16 (linear for global_load_lds,
// conflict-free ds_read_b128 - 0 conflicts measured r1-r6).
//
// Phase p: [stage][vm guard if cross-buffer lookahead][ds_reads for p+1]
//          [16 MFMA from regs][lgkmcnt(0)][s_barrier]
// Stage slots (= r3/r6, passed): P0: buf1.A-mh1<-kt1 | P1: buf0.B-h0<-kt2 |
//   P2: buf0.B-h1 | P3: buf0.A-mh0 | P4: buf0.A-mh1 | P5: buf1.B-h0<-kt3 |
//   P6: buf1.B-h1 | P7: buf1.A-mh0.
// vmcnt ledger (2 gloads/stage): at P3 after its stage, outstanding
// candidates = {P1,P2,P3} = 6 gloads; vmcnt(6) proves everything <= P0
// landed = buf1 complete (pieces staged P5/P6/P7 prev + P0 cur).  Last
// iteration: P1-P3 stages skipped -> vmcnt(6) proves nothing -> use vmcnt(0).
// At P7 after its stage: {P5,P6,P7} in flight; vmcnt(6) proves <= P4 landed
// = buf0@kt2 complete (staged P1-P4).
// WAR: every region's last ds_read now happens one phase BEFORE its old
// slot; each overwrite remains >= 2 barriers after the last read + lgkm0.
// ---------------------------------------------------------------------------
__device__ __forceinline__ void gload16(const _Float16* g, _Float16* l) {
  __builtin_amdgcn_global_load_lds(
      (const __attribute__((address_space(1))) void*)g,
      (__attribute__((address_space(3))) void*)l, 16, 0, 0);
}

#define BAR()   asm volatile("s_barrier" ::: "memory")
#define LGKM0() asm volatile("s_waitcnt lgkmcnt(0)" ::: "memory")
#define VM6()   asm volatile("s_waitcnt vmcnt(6)" ::: "memory")
#define VM0()   asm volatile("s_waitcnt vmcnt(0)" ::: "memory")

#define LA(BUF, X, MH, KS) \
  (*(const f16x8*)(lds + (BUF)*16384 + rA + (KS)*8192 + (MH)*512 + (X)*128))
#define LB(BUF, NR, KS) \
  (*(const f16x8*)(lds + 32768 + (BUF)*16384 + rB + (KS)*8192 + (NR)*128))

#define ALD(T0, T1, T2, T3, BUF, MH, KS) do { \
    T0 = LA(BUF, 0, MH, KS); T1 = LA(BUF, 1, MH, KS); \
    T2 = LA(BUF, 2, MH, KS); T3 = LA(BUF, 3, MH, KS); \
  } while (0)

#define BLD(CB, BUF) do { \
    CB[0][0]=LB(BUF,0,0); CB[1][0]=LB(BUF,1,0); \
    CB[2][0]=LB(BUF,2,0); CB[3][0]=LB(BUF,3,0); \
    CB[0][1]=LB(BUF,0,1); CB[1][1]=LB(BUF,1,1); \
    CB[2][1]=LB(BUF,2,1); CB[3][1]=LB(BUF,3,1); \
  } while (0)

#define MF(A, B, C) __builtin_amdgcn_mfma_f32_16x16x32_f16(A, B, C, 0, 0, 0)

#define MFMAS(A0, A1, A2, A3, CB, MH, KS) do { \
    __builtin_amdgcn_s_setprio(1); \
    acc[(MH)*4+0][0]=MF(A0,CB[0][KS],acc[(MH)*4+0][0]); \
    acc[(MH)*4+0][1]=MF(A0,CB[1][KS],acc[(MH)*4+0][1]); \
    acc[(MH)*4+0][2]=MF(A0,CB[2][KS],acc[(MH)*4+0][2]); \
    acc[(MH)*4+0][3]=MF(A0,CB[3][KS],acc[(MH)*4+0][3]); \
    acc[(MH)*4+1][0]=MF(A1,CB[0][KS],acc[(MH)*4+1][0]); \
    acc[(MH)*4+1][1]=MF(A1,CB[1][KS],acc[(MH)*4+1][1]); \
    acc[(MH)*4+1][2]=MF(A1,CB[2][KS],acc[(MH)*4+1][2]); \
    acc[(MH)*4+1][3]=MF(A1,CB[3][KS],acc[(MH)*4+1][3]); \
    acc[(MH)*4+2][0]=MF(A2,CB[0][KS],acc[(MH)*4+2][0]); \
    acc[(MH)*4+2][1]=MF(A2,CB[1][KS],acc[(MH)*4+2][1]); \
    acc[(MH)*4+2][2]=MF(A2,CB[2][KS],acc[(MH)*4+2][2]); \
    acc[(MH)*4+2][3]=MF(A2,CB[3][KS],acc[(MH)*4+2][3]); \
    acc[(MH)*4+3][0]=MF(A3,CB[0][KS],acc[(MH)*4+3][0]); \
    acc[(MH)*4+3][1]=MF(A3,CB[1][KS],acc[(MH)*4+3][1]); \
    acc[(MH)*4+3][2]=MF(A3,CB[2][KS],acc[(MH)*4+3][2]); \
    acc[(MH)*4+3][3]=MF(A3,CB[3][KS],acc[(MH)*4+3][3]); \
    __builtin_amdgcn_s_setprio(0); \
  } while (0)

__global__ __launch_bounds__(512, 2) void qkv_gemm_kernel(
    const _Float16* __restrict__ Ah, const _Float16* __restrict__ Wh,
    const float* __restrict__ qb, const float* __restrict__ kb,
    const float* __restrict__ vb, float* __restrict__ out) {
  extern __shared__ _Float16 lds[];   // 131072 B

  const int t    = threadIdx.x;
  const int lane = t & 63;
  const int wid  = t >> 6;            // 0..7
  const int wm   = wid >> 2;          // 0..1 (M)
  const int wn   = wid & 3;           // 0..3 (N)
  const int fr   = lane & 15;
  const int fq   = lane >> 4;

  const int n0  = blockIdx.x * 256;
  const int m0  = blockIdx.y * 256;
  const int p   = n0 >> 11;
  const int ln0 = n0 & (HD - 1);
  const _Float16* Ag  = Ah + (size_t)m0 * HD;
  const _Float16* Bgp = Wh + (size_t)p * HD * HD + (size_t)ln0 * HD;
  const float* bias = (p == 0) ? qb : (p == 1) ? kb : vb;

  // staging invariants: wave-linear dest (chunk = kb0*256 + rowbase + lane)
  const int kb0     = t >> 7;                         // 0..3
  const int rowbase = (t & 63) + ((t & 64) << 1);     // lane + (wid&1)*128
  const size_t goff = (size_t)rowbase * HD + kb0 * 8; // global f16 offset
  const int ldsC    = kb0 * 256 + rowbase;            // lds chunk

  // fragment-read invariants (f16 offsets within a buffer)
  const int rA = fq * 2048 + wm * 1024 + fr * 8;
  const int rB = fq * 2048 + wn * 512 + fr * 8;

  auto stA = [&](int buf, int hf, int kt) {
    const _Float16* g = Ag + goff + (size_t)(hf * 64) * HD + kt * 64;
    _Float16* l = lds + buf * 16384 + (ldsC + hf * 64) * 8;
    gload16(g, l); gload16(g + 32, l + 8192);
  };
  auto stB = [&](int buf, int hf, int kt) {
    const _Float16* g = Bgp + goff + (size_t)(hf * 64) * HD + kt * 64;
    _Float16* l = lds + 32768 + buf * 16384 + (ldsC + hf * 64) * 8;
    gload16(g, l); gload16(g + 32, l + 8192);
  };

  f32x4 acc[8][4] = {};

  // Fragment register sets (persist across phases; all constant-indexed).
  f16x8 x0, x1, x2, x3;        // A-frags, even phases' MFMA input
  f16x8 y0, y1, y2, y3;        // A-frags, odd phases' MFMA input
  f16x8 cbA[4][2], cbB[4][2];  // B-frags for buf0 / buf1 K-tiles

  // Prologue: buf0 <- K-tile 0 (4 halves), buf1 <- K-tile 1 (3 halves).
  // vmcnt(6) = 3 calls in flight -> buf0 fully landed.
  stB(0, 0, 0); stB(0, 1, 0); stA(0, 0, 0); stA(0, 1, 0);
  stB(1, 0, 1); stB(1, 1, 1); stA(1, 0, 1);
  VM6();
  BAR();
  // Preload P0's fragments (buf0): 8 B + 4 A.
  BLD(cbA, 0);
  ALD(x0, x1, x2, x3, 0, 0, 0);

#pragma unroll 1
  for (int i = 0; i < NIT; ++i) {
    const bool nl = (i < NIT - 1);
    const int kt1 = 2 * i + 1, kt2 = 2 * i + 2, kt3 = 2 * i + 3;

    // ---- P0: MFMA buf0(mh0,ks0); lookahead A(0,mh0,ks1) ----
    stA(1, 1, kt1);
    ALD(y0, y1, y2, y3, 0, 0, 1);
    MFMAS(x0, x1, x2, x3, cbA, 0, 0);
    LGKM0(); BAR();

    // ---- P1: MFMA buf0(mh0,ks1); lookahead A(0,mh1,ks0) ----
    if (nl) stB(0, 0, kt2);
    ALD(x0, x1, x2, x3, 0, 1, 0);
    MFMAS(y0, y1, y2, y3, cbA, 0, 1);
    LGKM0(); BAR();

    // ---- P2: MFMA buf0(mh1,ks0); lookahead A(0,mh1,ks1) ----
    if (nl) stB(0, 1, kt2);
    ALD(y0, y1, y2, y3, 0, 1, 1);
    MFMAS(x0, x1, x2, x3, cbA, 1, 0);
    LGKM0(); BAR();

    // ---- P3: MFMA buf0(mh1,ks1); guard buf1; lookahead B1 + A(1,mh0,ks0) --
    if (nl) stA(0, 0, kt2);
    if (nl) { VM6(); } else { VM0(); }       // buf1 content landed
    BLD(cbB, 1);
    ALD(x0, x1, x2, x3, 1, 0, 0);
    MFMAS(y0, y1, y2, y3, cbA, 1, 1);
    LGKM0(); BAR();

    // ---- P4: MFMA buf1(mh0,ks0); lookahead A(1,mh0,ks1) ----
    if (nl) stA(0, 1, kt2);
    ALD(y0, y1, y2, y3, 1, 0, 1);
    MFMAS(x0, x1, x2, x3, cbB, 0, 0);
    LGKM0(); BAR();

    // ---- P5: MFMA buf1(mh0,ks1); lookahead A(1,mh1,ks0) ----
    if (nl) stB(1, 0, kt3);
    ALD(x0, x1, x2, x3, 1, 1, 0);
    MFMAS(y0, y1, y2, y3, cbB, 0, 1);
    LGKM0(); BAR();

    // ---- P6: MFMA buf1(mh1,ks0); lookahead A(1,mh1,ks1) ----
    if (nl) stB(1, 1, kt3);
    ALD(y0, y1, y2, y3, 1, 1, 1);
    MFMAS(x0, x1, x2, x3, cbB, 1, 0);
    LGKM0(); BAR();

    // ---- P7: MFMA buf1(mh1,ks1); guard buf0@kt2; lookahead B0' + A ----
    if (nl) {
      stA(1, 0, kt3);
      VM6();                                 // buf0@kt2 landed
      BLD(cbA, 0);
      ALD(x0, x1, x2, x3, 0, 0, 0);
    }
    MFMAS(y0, y1, y2, y3, cbB, 1, 1);
    LGKM0(); BAR();
  }

  // Epilogue: C/D layout col = lane&15, row = (lane>>4)*4 + reg.
  float bv[4];
#pragma unroll
  for (int nr = 0; nr < 4; ++nr)
    bv[nr] = bias[(ln0 + wn * 64 + nr * 16 + fr)];
#pragma unroll
  for (int mr = 0; mr < 8; ++mr) {
    const int r0 = m0 + wm * 128 + mr * 16 + fq * 4;
#pragma unroll
    for (int nr = 0; nr < 4; ++nr) {
      const int cg = n0 + wn * 64 + nr * 16 + fr;
      f32x4 v = acc[mr][nr];
#pragma unroll
      for (int r = 0; r < 4; ++r)
        out[(size_t)(r0 + r) * NTOT + cg] = v[r] + bv[nr];
    }
  }
}

// ---------------------------------------------------------------------------
extern "C" void kernel_launch(void* const* d_in, const int* in_sizes, int n_in,
                              void* d_out, int out_size, void* d_ws,
                              size_t ws_size, hipStream_t stream) {
  const float* x     = (const float*)d_in[0];
  const float* gamma = (const float*)d_in[1];
  const float* beta  = (const float*)d_in[2];
  const float* qw    = (const float*)d_in[3];
  const float* qb    = (const float*)d_in[4];
  const float* kw    = (const float*)d_in[5];
  const float* kbia  = (const float*)d_in[6];
  const float* vw    = (const float*)d_in[7];
  const float* vb    = (const float*)d_in[8];
  float* out = (float*)d_out;

  // Workspace: [0, 32M) normed fp16 [8192][2048]; [32M, 56M) W fp16 [3][2048][2048]
  char* ws = (char*)d_ws;
  _Float16* Ahp = (_Float16*)(ws);
  _Float16* Whp = (_Float16*)(ws + (size_t)MTOT * HD * 2);

  (void)hipFuncSetAttribute((const void*)qkv_gemm_kernel,
                            hipFuncAttributeMaxDynamicSharedMemorySize, 131072);

  ln_f16_kernel<<<MTOT, 256, 0, stream>>>(x, gamma, beta, Ahp);
  w_f16_kernel<<<dim3(1024, 3), 256, 0, stream>>>(qw, kw, vw, Whp);
  qkv_gemm_kernel<<<dim3(NTOT / 256, MTOT / 256), 512, 131072, stream>>>(
      Ahp, Whp, qb, kbia, vb, out);
}